// Round 1
// baseline (196.913 us; speedup 1.0000x reference)
//
#include <hip/hip_runtime.h>
#include <hip/hip_bf16.h>

// Problem constants
#define B_SZ   16
#define V_IN   1024
#define V_OUT  4096
#define C_IN   128
#define C_OUT  256
#define K_NB   18
#define NNZ    16384
#define K_GEMM (K_NB * C_IN)   // 2304
#define BK     64
#define N_IT   (K_GEMM / BK)   // 36

typedef __attribute__((ext_vector_type(8))) short bf16x8;   // 8 bf16 = 4 VGPRs
typedef __attribute__((ext_vector_type(4))) float f32x4;

// ---------------- CSR build ----------------
__global__ void zero_counts_kernel(int* counts) {
    int i = blockIdx.x * blockDim.x + threadIdx.x;
    if (i < V_OUT) counts[i] = 0;
}

__global__ void hist_kernel(const int* __restrict__ rows, int* counts) {
    int n = blockIdx.x * blockDim.x + threadIdx.x;
    if (n < NNZ) atomicAdd(&counts[rows[n]], 1);
}

__global__ void scan_kernel(const int* __restrict__ counts, int* offsets, int* cursor) {
    __shared__ int s[1024];
    int t = threadIdx.x;
    int base = t * 4;
    int c0 = counts[base], c1 = counts[base + 1], c2 = counts[base + 2], c3 = counts[base + 3];
    int tot = c0 + c1 + c2 + c3;
    s[t] = tot;
    __syncthreads();
    for (int d = 1; d < 1024; d <<= 1) {
        int v = (t >= d) ? s[t - d] : 0;
        __syncthreads();
        s[t] += v;
        __syncthreads();
    }
    int excl = s[t] - tot;
    offsets[base]     = excl;
    offsets[base + 1] = excl + c0;
    offsets[base + 2] = excl + c0 + c1;
    offsets[base + 3] = excl + c0 + c1 + c2;
    cursor[base]     = excl;
    cursor[base + 1] = excl + c0;
    cursor[base + 2] = excl + c0 + c1;
    cursor[base + 3] = excl + c0 + c1 + c2;
    if (t == 1023) offsets[V_OUT] = s[1023];
}

__global__ void fill_kernel(const int* __restrict__ rows, int* cursor, int* perm) {
    int n = blockIdx.x * blockDim.x + threadIdx.x;
    if (n < NNZ) {
        int r = rows[n];
        int pos = atomicAdd(&cursor[r], 1);
        perm[pos] = n;
    }
}

// ---------------- pooling (gather form) ----------------
// pool[b][r][c] = sum_{n: rows[n]==r} vals[n] * x[b][cols[n]][c]   -> bf16
__global__ void pool_kernel(const float* __restrict__ x, const float* __restrict__ vals,
                            const int* __restrict__ cols, const int* __restrict__ offsets,
                            const int* __restrict__ perm, __hip_bfloat16* __restrict__ pool) {
    int r = blockIdx.x;
    int b = blockIdx.y;
    int c = threadIdx.x;
    int j0 = offsets[r], j1 = offsets[r + 1];
    float acc = 0.f;
    for (int j = j0; j < j1; ++j) {
        int n = perm[j];
        acc += vals[n] * x[((size_t)b * V_IN + cols[n]) * C_IN + c];
    }
    pool[((size_t)b * V_OUT + r) * C_IN + c] = __float2bfloat16(acc);
}

// ---------------- combined weight (transposed) ----------------
// wT[c][r], c in [0,256), r in [0,2304)
// cols 0..127: Wf ; 128..191: W2d3 (rows<1536) ; 192..255: Wd3 (rows<768); + W1 for rows<128
__global__ void wcomb_kernel(const float* __restrict__ W1, const float* __restrict__ Wd3,
                             const float* __restrict__ W2d3, const float* __restrict__ Wf,
                             __hip_bfloat16* __restrict__ wT) {
    int e = blockIdx.x * blockDim.x + threadIdx.x;
    if (e >= C_OUT * K_GEMM) return;
    int c = e / K_GEMM;
    int r = e - c * K_GEMM;
    float v;
    if (c < 128)       v = Wf[r * 128 + c];
    else if (c < 192)  v = (r < 1536) ? W2d3[r * 64 + (c - 128)] : 0.f;
    else               v = (r < 768)  ? Wd3[r * 64 + (c - 192)]  : 0.f;
    if (r < 128) v += W1[r * 256 + c];
    wT[e] = __float2bfloat16(v);
}

__global__ void bias_kernel(const float* __restrict__ b1, const float* __restrict__ bd3,
                            const float* __restrict__ b2d3, const float* __restrict__ bf,
                            float* __restrict__ bias) {
    int c = threadIdx.x;
    float v = b1[c];
    if (c < 128)      v += bf[c];
    else if (c < 192) v += b2d3[c - 128];
    else              v += bd3[c - 192];
    bias[c] = v;
}

// ---------------- gathered GEMM with relu epilogue ----------------
// out[(b*4096+v)][n] = relu( sum_k A[m][k]*Wcomb[k][n] + bias[n] )
// A[m][k] = pool[b][ spiral[v][k/128] ][ k%128 ]
__global__ __launch_bounds__(256) void gemm_kernel(
    const __hip_bfloat16* __restrict__ pool,    // [16][4096][128] bf16
    const __hip_bfloat16* __restrict__ wT,      // [256][2304] bf16
    const float* __restrict__ bias,             // [256]
    const int* __restrict__ spiral,             // [4096][18]
    float* __restrict__ out)                    // [16][4096][256] f32
{
    __shared__ __hip_bfloat16 As[128 * BK];   // [row m][k] linear
    __shared__ __hip_bfloat16 Bs[128 * BK];   // [row n][k] linear (wT layout)

    const int tid  = threadIdx.x;
    const int lane = tid & 63;
    const int bm   = blockIdx.y;              // 0..511
    const int n0   = blockIdx.x * 128;        // 0 or 128
    const int b    = bm >> 5;                 // 32 m-tiles per batch
    const int v0   = (bm & 31) << 7;
    const int wid  = tid >> 6;
    const int wm   = (wid >> 1) << 6;         // wave row offset within tile
    const int wn   = (wid & 1) << 6;          // wave col offset within tile

    const __hip_bfloat16* poolB = pool + (size_t)b * V_OUT * C_IN;

    f32x4 acc[4][4] = {};

    auto stageAB = [&](int it) {
        const int k0 = it << 6;          // global k base
        const int j  = k0 >> 7;          // neighbor index (BK=64 stays within one neighbor)
        const int c0 = k0 & 127;         // channel base (0 or 64)
#pragma unroll
        for (int ch = 0; ch < 4; ++ch) {
            int flat = ch * 256 + tid;       // 16B chunk id; lanes consecutive within wave
            int r    = flat >> 3;            // tile row 0..127
            int k8   = (flat & 7) << 3;      // k offset within BK
            int sidx = spiral[(v0 + r) * K_NB + j];
            const __hip_bfloat16* srcA = poolB + ((size_t)sidx * C_IN + c0 + k8);
            __builtin_amdgcn_global_load_lds(
                (const __attribute__((address_space(1))) unsigned int*)srcA,
                (__attribute__((address_space(3))) unsigned int*)(As + flat * 8),
                16, 0, 0);
            const __hip_bfloat16* srcB = wT + ((size_t)(n0 + r) * K_GEMM + k0 + k8);
            __builtin_amdgcn_global_load_lds(
                (const __attribute__((address_space(1))) unsigned int*)srcB,
                (__attribute__((address_space(3))) unsigned int*)(Bs + flat * 8),
                16, 0, 0);
        }
    };

    stageAB(0);
    for (int it = 0; it < N_IT; ++it) {
        __syncthreads();   // staging complete (implicit vmcnt(0) before barrier)
#pragma unroll
        for (int ks = 0; ks < 2; ++ks) {
            bf16x8 af[4], bg[4];
#pragma unroll
            for (int i = 0; i < 4; ++i) {
                af[i] = *(const bf16x8*)(As + (wm + i * 16 + (lane & 15)) * BK + ks * 32 + ((lane >> 4) << 3));
                bg[i] = *(const bf16x8*)(Bs + (wn + i * 16 + (lane & 15)) * BK + ks * 32 + ((lane >> 4) << 3));
            }
#pragma unroll
            for (int mi = 0; mi < 4; ++mi)
#pragma unroll
                for (int ni = 0; ni < 4; ++ni)
                    acc[mi][ni] = __builtin_amdgcn_mfma_f32_16x16x32_bf16(af[mi], bg[ni], acc[mi][ni], 0, 0, 0);
        }
        __syncthreads();   // all waves done reading LDS
        if (it + 1 < N_IT) stageAB(it + 1);
    }

    // epilogue: +bias, relu, store f32
#pragma unroll
    for (int ni = 0; ni < 4; ++ni) {
        int col = n0 + wn + ni * 16 + (lane & 15);
        float bz = bias[col];
#pragma unroll
        for (int mi = 0; mi < 4; ++mi) {
#pragma unroll
            for (int r4 = 0; r4 < 4; ++r4) {
                int mrow = wm + mi * 16 + ((lane >> 4) << 2) + r4;
                float v = acc[mi][ni][r4] + bz;
                v = v > 0.f ? v : 0.f;
                out[((size_t)(b * V_OUT + v0 + mrow)) * C_OUT + col] = v;
            }
        }
    }
}

extern "C" void kernel_launch(void* const* d_in, const int* in_sizes, int n_in,
                              void* d_out, int out_size, void* d_ws, size_t ws_size,
                              hipStream_t stream) {
    const float* x     = (const float*)d_in[0];
    const float* vals  = (const float*)d_in[1];
    const float* W1    = (const float*)d_in[2];
    const float* b1    = (const float*)d_in[3];
    const float* Wd3   = (const float*)d_in[4];
    const float* bd3   = (const float*)d_in[5];
    const float* W2d3  = (const float*)d_in[6];
    const float* b2d3  = (const float*)d_in[7];
    const float* Wf    = (const float*)d_in[8];
    const float* bf    = (const float*)d_in[9];
    const int*   rows  = (const int*)d_in[10];
    const int*   cols  = (const int*)d_in[11];
    const int*   spiral= (const int*)d_in[12];
    float* out = (float*)d_out;

    // workspace layout
    char* ws = (char*)d_ws;
    __hip_bfloat16* pool = (__hip_bfloat16*)ws;                              // 16,777,216 B
    __hip_bfloat16* wT   = (__hip_bfloat16*)(ws + 16777216);                 //  1,179,648 B
    float* bias          = (float*)(ws + 16777216 + 1179648);                //      1,024 B
    int*   counts        = (int*)(ws + 16777216 + 1179648 + 1024);
    int*   offsets       = counts + V_OUT;          // V_OUT+1 ints
    int*   cursor        = offsets + V_OUT + 4;     // padded
    int*   perm          = cursor + V_OUT;

    zero_counts_kernel<<<(V_OUT + 255) / 256, 256, 0, stream>>>(counts);
    hist_kernel<<<NNZ / 256, 256, 0, stream>>>(rows, counts);
    scan_kernel<<<1, 1024, 0, stream>>>(counts, offsets, cursor);
    fill_kernel<<<NNZ / 256, 256, 0, stream>>>(rows, cursor, perm);
    pool_kernel<<<dim3(V_OUT, B_SZ), C_IN, 0, stream>>>(x, vals, cols, offsets, perm, pool);
    wcomb_kernel<<<(C_OUT * K_GEMM + 255) / 256, 256, 0, stream>>>(W1, Wd3, W2d3, Wf, wT);
    bias_kernel<<<1, C_OUT, 0, stream>>>(b1, bd3, b2d3, bf, bias);
    gemm_kernel<<<dim3(2, 512), 256, 0, stream>>>(pool, wT, bias, spiral, out);
}

// Round 2
// 111.959 us; speedup vs baseline: 1.7588x; 1.7588x over previous
//
#include <hip/hip_runtime.h>
#include <hip/hip_bf16.h>

// Problem constants
#define B_SZ   16
#define V_IN   1024
#define V_OUT  4096
#define C_IN   128
#define C_OUT  256
#define K_NB   18
#define NNZ    16384
#define K_GEMM (K_NB * C_IN)   // 2304
#define BK     64
#define NKT    (K_GEMM / BK)   // 36

typedef __attribute__((ext_vector_type(8))) short bf16x8;   // 8 bf16 = 4 VGPRs
typedef __attribute__((ext_vector_type(4))) float f32x4;

#define GLOAD16(src, dst) __builtin_amdgcn_global_load_lds( \
    (const __attribute__((address_space(1))) unsigned int*)(src), \
    (__attribute__((address_space(3))) unsigned int*)(dst), 16, 0, 0)

// ---------------- CSR build ----------------
__global__ void zero_counts_kernel(int* counts) {
    int i = blockIdx.x * blockDim.x + threadIdx.x;
    if (i < V_OUT) counts[i] = 0;
}

__global__ void hist_kernel(const int* __restrict__ rows, int* counts) {
    int n = blockIdx.x * blockDim.x + threadIdx.x;
    if (n < NNZ) atomicAdd(&counts[rows[n]], 1);
}

__global__ void scan_kernel(const int* __restrict__ counts, int* offsets, int* cursor) {
    __shared__ int s[1024];
    int t = threadIdx.x;
    int base = t * 4;
    int c0 = counts[base], c1 = counts[base + 1], c2 = counts[base + 2], c3 = counts[base + 3];
    int tot = c0 + c1 + c2 + c3;
    s[t] = tot;
    __syncthreads();
    for (int d = 1; d < 1024; d <<= 1) {
        int v = (t >= d) ? s[t - d] : 0;
        __syncthreads();
        s[t] += v;
        __syncthreads();
    }
    int excl = s[t] - tot;
    offsets[base]     = excl;
    offsets[base + 1] = excl + c0;
    offsets[base + 2] = excl + c0 + c1;
    offsets[base + 3] = excl + c0 + c1 + c2;
    cursor[base]     = excl;
    cursor[base + 1] = excl + c0;
    cursor[base + 2] = excl + c0 + c1;
    cursor[base + 3] = excl + c0 + c1 + c2;
    if (t == 1023) offsets[V_OUT] = s[1023];
}

__global__ void fill_kernel(const int* __restrict__ rows, int* cursor, int* perm) {
    int n = blockIdx.x * blockDim.x + threadIdx.x;
    if (n < NNZ) {
        int r = rows[n];
        int pos = atomicAdd(&cursor[r], 1);
        perm[pos] = n;
    }
}

// ---------------- pooling: one block per out-row, 16 batch accumulators ----------------
__global__ __launch_bounds__(128) void pool_kernel(
    const float* __restrict__ x, const float* __restrict__ vals,
    const int* __restrict__ cols, const int* __restrict__ offsets,
    const int* __restrict__ perm, __hip_bfloat16* __restrict__ pool) {
    int r = blockIdx.x;
    int c = threadIdx.x;
    int j0 = offsets[r], j1 = offsets[r + 1];
    float acc[B_SZ];
#pragma unroll
    for (int b = 0; b < B_SZ; ++b) acc[b] = 0.f;
    for (int j = j0; j < j1; ++j) {
        int n = perm[j];
        float v = vals[n];
        const float* xp = x + (size_t)cols[n] * C_IN + c;
#pragma unroll
        for (int b = 0; b < B_SZ; ++b) acc[b] += v * xp[(size_t)b * V_IN * C_IN];
    }
#pragma unroll
    for (int b = 0; b < B_SZ; ++b)
        pool[((size_t)b * V_OUT + r) * C_IN + c] = __float2bfloat16(acc[b]);
}

// ---------------- combined weight, pre-swizzled per-K-tile LDS image ----------------
// wTs[kt][chunk c][e]: chunk c -> (nrow = c>>3, kslot = (c&7)*16);
// logical kbyte = kslot ^ ((nrow&7)<<4); k = kt*64 + kbyte/2 + e; col = nrow.
__global__ void wcomb_kernel(const float* __restrict__ W1, const float* __restrict__ Wd3,
                             const float* __restrict__ W2d3, const float* __restrict__ Wf,
                             __hip_bfloat16* __restrict__ wTs) {
    int idx = blockIdx.x * blockDim.x + threadIdx.x;       // 0 .. 36*16384-1
    if (idx >= NKT * 16384) return;
    int kt = idx >> 14;
    int c  = (idx >> 3) & 2047;
    int e  = idx & 7;
    int nrow  = c >> 3;
    int kslot = (c & 7) << 4;
    int kb = kslot ^ ((nrow & 7) << 4);
    int r  = kt * 64 + (kb >> 1) + e;    // global k, 0..2303
    int col = nrow;
    float v;
    if (col < 128)      v = Wf[r * 128 + col];
    else if (col < 192) v = (r < 1536) ? W2d3[r * 64 + (col - 128)] : 0.f;
    else                v = (r < 768)  ? Wd3[r * 64 + (col - 192)]  : 0.f;
    if (r < 128) v += W1[r * 256 + col];
    wTs[idx] = __float2bfloat16(v);
}

__global__ void bias_kernel(const float* __restrict__ b1, const float* __restrict__ bd3,
                            const float* __restrict__ b2d3, const float* __restrict__ bf,
                            float* __restrict__ bias) {
    int c = threadIdx.x;
    float v = b1[c];
    if (c < 128)      v += bf[c];
    else if (c < 192) v += b2d3[c - 128];
    else              v += bd3[c - 192];
    bias[c] = v;
}

// ---------------- gathered GEMM: 256x256 tile, counted-vmcnt pipeline ----------------
__global__ __launch_bounds__(512, 2) void gemm_kernel(
    const __hip_bfloat16* __restrict__ pool,    // [16][4096][128] bf16
    const __hip_bfloat16* __restrict__ wTs,     // [36][16384] bf16, pre-swizzled K-tile images
    const float* __restrict__ bias,             // [256]
    const int* __restrict__ spiral,             // [4096][18]
    float* __restrict__ out)                    // [16][4096][256] f32
{
    // LDS: A slots @0,32768 ; B slots @65536,98304 ; spiral cache @131072 (18432B)
    __shared__ __align__(16) char smem[149504];
    int* spl = (int*)(smem + 131072);

    const int tid  = threadIdx.x;
    const int lane = tid & 63;
    const int wid  = tid >> 6;
    const int wm   = (wid >> 2) << 7;     // 0 / 128
    const int wn   = (wid & 3) << 6;      // 0,64,128,192

    const int bid = blockIdx.x;
    const int bm  = ((bid & 7) << 5) + (bid >> 3);   // bijective XCD swizzle (256 = 8*32)
    const int b   = bm >> 4;                          // batch
    const int v0  = (bm & 15) << 8;                   // m-tile origin within batch

    // cache this block's spiral rows in LDS: 256 rows x 18
    for (int i = tid; i < 256 * K_NB; i += 512) spl[i] = spiral[v0 * K_NB + i];
    __syncthreads();

    const char* poolBytes = (const char*)(pool + (size_t)b * V_OUT * C_IN);
    const char* wTsBytes  = (const char*)wTs;
    const int tg3 = tid >> 3;                              // 0..63 (row-in-64 group)
    const int sb  = ((tid & 7) << 4) ^ ((tg3 & 7) << 4);   // inverse-swizzled col byte

    auto stageA = [&](int kt) {
        const int j   = kt >> 1;
        const int c0b = (kt & 1) << 7;
        char* dst = smem + ((kt & 1) << 15);
#pragma unroll
        for (int ch = 0; ch < 4; ++ch) {
            int sidx = spl[(ch * 64 + tg3) * K_NB + j];
            GLOAD16(poolBytes + ((size_t)sidx << 8) + (c0b + sb),
                    dst + ((ch << 9) + tid) * 16);
        }
    };
    auto stageB = [&](int kt) {
        const char* src = wTsBytes + ((size_t)kt << 15) + tid * 16;
        char* dst = smem + 65536 + ((kt & 1) << 15);
#pragma unroll
        for (int ch = 0; ch < 4; ++ch)
            GLOAD16(src + (ch << 13), dst + (ch << 13) + tid * 16);
    };

    // per-lane fragment-read constants
    const int l15   = lane & 15;
    const int swm   = (lane & 7) << 4;          // row&7 == lane&7 for all frag rows
    const int klane = (lane >> 4) << 4;         // 0,16,32,48
    const int aRow  = (wm + l15) << 7;          // byte offset of lane's A row base
    const int bRow  = (wn + l15) << 7;

    f32x4 acc[8][4] = {};

    stageA(0);
    stageB(0);

#pragma unroll 2
    for (int kt = 0; kt < NKT; ++kt) {
        const int s = kt & 1;
        const char* As = smem + (s << 15);
        const char* Bs = smem + 65536 + (s << 15);

        if (kt + 1 < NKT) {
            stageA(kt + 1);
            asm volatile("s_waitcnt vmcnt(4)" ::: "memory");
        } else {
            asm volatile("s_waitcnt vmcnt(0)" ::: "memory");
        }
        __builtin_amdgcn_s_barrier();
        __builtin_amdgcn_sched_barrier(0);

        bf16x8 a[8], b0, b1;
        // ---- phase 1: ks=0, ni 0,1 ----
#pragma unroll
        for (int mi = 0; mi < 8; ++mi)
            a[mi] = *(const bf16x8*)(As + aRow + (mi << 11) + ((0 + klane) ^ swm));
        b0 = *(const bf16x8*)(Bs + bRow + (0 << 11) + ((0 + klane) ^ swm));
        b1 = *(const bf16x8*)(Bs + bRow + (1 << 11) + ((0 + klane) ^ swm));
        __builtin_amdgcn_s_setprio(1);
#pragma unroll
        for (int mi = 0; mi < 8; ++mi) {
            acc[mi][0] = __builtin_amdgcn_mfma_f32_16x16x32_bf16(a[mi], b0, acc[mi][0], 0, 0, 0);
            acc[mi][1] = __builtin_amdgcn_mfma_f32_16x16x32_bf16(a[mi], b1, acc[mi][1], 0, 0, 0);
        }
        __builtin_amdgcn_s_setprio(0);
        // ---- phase 2: ks=0, ni 2,3 ----
        b0 = *(const bf16x8*)(Bs + bRow + (2 << 11) + ((0 + klane) ^ swm));
        b1 = *(const bf16x8*)(Bs + bRow + (3 << 11) + ((0 + klane) ^ swm));
        __builtin_amdgcn_s_setprio(1);
#pragma unroll
        for (int mi = 0; mi < 8; ++mi) {
            acc[mi][2] = __builtin_amdgcn_mfma_f32_16x16x32_bf16(a[mi], b0, acc[mi][2], 0, 0, 0);
            acc[mi][3] = __builtin_amdgcn_mfma_f32_16x16x32_bf16(a[mi], b1, acc[mi][3], 0, 0, 0);
        }
        __builtin_amdgcn_s_setprio(0);
        // ---- stage B(kt+1) mid-tile ----
        if (kt + 1 < NKT) stageB(kt + 1);
        // ---- phase 3: ks=1, ni 0,1 ----
#pragma unroll
        for (int mi = 0; mi < 8; ++mi)
            a[mi] = *(const bf16x8*)(As + aRow + (mi << 11) + ((64 + klane) ^ swm));
        b0 = *(const bf16x8*)(Bs + bRow + (0 << 11) + ((64 + klane) ^ swm));
        b1 = *(const bf16x8*)(Bs + bRow + (1 << 11) + ((64 + klane) ^ swm));
        __builtin_amdgcn_s_setprio(1);
#pragma unroll
        for (int mi = 0; mi < 8; ++mi) {
            acc[mi][0] = __builtin_amdgcn_mfma_f32_16x16x32_bf16(a[mi], b0, acc[mi][0], 0, 0, 0);
            acc[mi][1] = __builtin_amdgcn_mfma_f32_16x16x32_bf16(a[mi], b1, acc[mi][1], 0, 0, 0);
        }
        __builtin_amdgcn_s_setprio(0);
        // ---- phase 4: ks=1, ni 2,3 ----
        b0 = *(const bf16x8*)(Bs + bRow + (2 << 11) + ((64 + klane) ^ swm));
        b1 = *(const bf16x8*)(Bs + bRow + (3 << 11) + ((64 + klane) ^ swm));
        __builtin_amdgcn_s_setprio(1);
#pragma unroll
        for (int mi = 0; mi < 8; ++mi) {
            acc[mi][2] = __builtin_amdgcn_mfma_f32_16x16x32_bf16(a[mi], b0, acc[mi][2], 0, 0, 0);
            acc[mi][3] = __builtin_amdgcn_mfma_f32_16x16x32_bf16(a[mi], b1, acc[mi][3], 0, 0, 0);
        }
        __builtin_amdgcn_s_setprio(0);
        __builtin_amdgcn_s_barrier();        // end of K-tile: slot reads complete
        __builtin_amdgcn_sched_barrier(0);
    }

    // epilogue: +bias, relu, store f32
#pragma unroll
    for (int ni = 0; ni < 4; ++ni) {
        int col = wn + ni * 16 + l15;
        float bz = bias[col];
#pragma unroll
        for (int mi = 0; mi < 8; ++mi) {
            int row0 = v0 + wm + mi * 16 + ((lane >> 4) << 2);
#pragma unroll
            for (int r4 = 0; r4 < 4; ++r4) {
                float v = acc[mi][ni][r4] + bz;
                out[((size_t)(b * V_OUT + row0 + r4)) * C_OUT + col] = v > 0.f ? v : 0.f;
            }
        }
    }
}

extern "C" void kernel_launch(void* const* d_in, const int* in_sizes, int n_in,
                              void* d_out, int out_size, void* d_ws, size_t ws_size,
                              hipStream_t stream) {
    const float* x     = (const float*)d_in[0];
    const float* vals  = (const float*)d_in[1];
    const float* W1    = (const float*)d_in[2];
    const float* b1    = (const float*)d_in[3];
    const float* Wd3   = (const float*)d_in[4];
    const float* bd3   = (const float*)d_in[5];
    const float* W2d3  = (const float*)d_in[6];
    const float* b2d3  = (const float*)d_in[7];
    const float* Wf    = (const float*)d_in[8];
    const float* bf    = (const float*)d_in[9];
    const int*   rows  = (const int*)d_in[10];
    const int*   cols  = (const int*)d_in[11];
    const int*   spiral= (const int*)d_in[12];
    float* out = (float*)d_out;

    // workspace layout
    char* ws = (char*)d_ws;
    __hip_bfloat16* pool = (__hip_bfloat16*)ws;                              // 16,777,216 B
    __hip_bfloat16* wTs  = (__hip_bfloat16*)(ws + 16777216);                 //  1,179,648 B
    float* bias          = (float*)(ws + 16777216 + 1179648);                //      1,024 B
    int*   counts        = (int*)(ws + 16777216 + 1179648 + 1024);
    int*   offsets       = counts + V_OUT;          // V_OUT+1 ints
    int*   cursor        = offsets + V_OUT + 4;     // padded
    int*   perm          = cursor + V_OUT;

    zero_counts_kernel<<<(V_OUT + 255) / 256, 256, 0, stream>>>(counts);
    hist_kernel<<<NNZ / 256, 256, 0, stream>>>(rows, counts);
    scan_kernel<<<1, 1024, 0, stream>>>(counts, offsets, cursor);
    fill_kernel<<<NNZ / 256, 256, 0, stream>>>(rows, cursor, perm);
    pool_kernel<<<V_OUT, C_IN, 0, stream>>>(x, vals, cols, offsets, perm, pool);
    wcomb_kernel<<<(NKT * 16384 + 255) / 256, 256, 0, stream>>>(W1, Wd3, W2d3, Wf, wTs);
    bias_kernel<<<1, C_OUT, 0, stream>>>(b1, bd3, b2d3, bf, bias);
    gemm_kernel<<<256, 512, 0, stream>>>(pool, wTs, bias, spiral, out);
}